// Round 1
// baseline (45.947 us; speedup 1.0000x reference)
//
#include <hip/hip_runtime.h>
#include <math.h>

#define BATCH 32
#define ND 512
#define NC 100
#define JB 10
#define NJT 10          // NC / JB
#define NG 4            // n-groups per block
#define NTHREADS 512
#define BIGNEG 1000000.0f

__global__ __launch_bounds__(NTHREADS) void adv_main(
    const float* __restrict__ z, const float* __restrict__ wu,
    const float* __restrict__ bu, const float* __restrict__ wl,
    const float* __restrict__ bl, const float* __restrict__ y,
    float* __restrict__ ws)
{
  const int jt = blockIdx.x;      // j-tile 0..NJT-1
  const int b  = blockIdx.y;      // batch
  const int tid = threadIdx.x;
  const int g    = tid >> 7;      // n-group 0..3 (128 n's each)
  const int lane = tid & 127;     // i index (active if < NC)

  __shared__ __align__(16) float s_cr[ND][2];        // center/radius interleaved
  __shared__ __align__(16) float s_wl[ND][12];       // 10 j's, padded to 12 (48B rows)
  __shared__ __align__(16) float s_red[NG-1][128][12];
  __shared__ float s_max[NTHREADS/64];

  // stage center/radius
  const float* zb = z + b * (2 * ND);
  for (int n = tid; n < ND; n += NTHREADS) {
    float lo = zb[n], hi = zb[ND + n];
    s_cr[n][0] = 0.5f * (lo + hi);
    s_cr[n][1] = 0.5f * (hi - lo);
  }
  // stage w_l columns jt*JB .. jt*JB+9 for all n
  const float* wlb = wl + (size_t)b * ND * NC + jt * JB;
  for (int idx = tid; idx < ND * JB; idx += NTHREADS) {
    int n = idx / JB, jj = idx - n * JB;
    s_wl[n][jj] = wlb[n * NC + jj];
  }
  __syncthreads();

  float acc[JB];
#pragma unroll
  for (int jj = 0; jj < JB; ++jj) acc[jj] = 0.0f;

  const int i = lane;
  const bool act = (i < NC);
  if (act) {
    const float* wub = wu + (size_t)b * ND * NC + i;
    const int n0 = g * (ND / NG), n1 = n0 + ND / NG;
#pragma unroll 2
    for (int n = n0; n < n1; ++n) {
      float w = wub[n * NC];                       // coalesced, L2-resident
      float c = s_cr[n][0], r = s_cr[n][1];        // ds_read_b64, broadcast
      float4 a0 = *(const float4*)&s_wl[n][0];     // ds_read_b128, broadcast
      float4 a1 = *(const float4*)&s_wl[n][4];
      float2 a2 = *(const float2*)&s_wl[n][8];
      float wlv[JB] = {a0.x, a0.y, a0.z, a0.w, a1.x, a1.y, a1.z, a1.w, a2.x, a2.y};
#pragma unroll
      for (int jj = 0; jj < JB; ++jj) {
        float d = w - wlv[jj];
        acc[jj] = fmaf(c, d, fmaf(r, fabsf(d), acc[jj]));
      }
    }
  }

  // cross-n-group reduction: groups 1..3 dump, group 0 adds
  if (g > 0) {
#pragma unroll
    for (int jj = 0; jj < JB; ++jj) s_red[g - 1][lane][jj] = acc[jj];
  }
  __syncthreads();

  float m = -INFINITY;
  if (g == 0 && act) {
    const float* bub = bu + b * NC;
    const float* blb = bl + b * NC;
    const float* yb  = y  + b * NC;
    float base_i = bub[i] - BIGNEG * yb[i];        // -BIG*(1-target)[i] = -BIG*y[i]
#pragma unroll
    for (int jj = 0; jj < JB; ++jj) {
      int j = jt * JB + jj;
      float t = acc[jj] + s_red[0][lane][jj] + s_red[1][lane][jj] + s_red[2][lane][jj];
      float v = t + base_i - blb[j] - BIGNEG * (1.0f - yb[j]);
      m = fmaxf(m, v);
    }
  }

  // block max-reduce (inactive threads carry -inf)
#pragma unroll
  for (int off = 32; off; off >>= 1) m = fmaxf(m, __shfl_down(m, off, 64));
  if ((tid & 63) == 0) s_max[tid >> 6] = m;
  __syncthreads();
  if (tid == 0) {
    float r = s_max[0];
#pragma unroll
    for (int wv = 1; wv < NTHREADS / 64; ++wv) r = fmaxf(r, s_max[wv]);
    ws[b * NJT + jt] = r;
  }
}

__global__ void adv_reduce(const float* __restrict__ ws, float* __restrict__ out) {
  int b = threadIdx.x;
  if (b < BATCH) {
    float m = -INFINITY;
#pragma unroll
    for (int jt = 0; jt < NJT; ++jt) m = fmaxf(m, ws[b * NJT + jt]);
    out[b] = m;
  }
}

extern "C" void kernel_launch(void* const* d_in, const int* in_sizes, int n_in,
                              void* d_out, int out_size, void* d_ws, size_t ws_size,
                              hipStream_t stream) {
  // inputs: 0:x (unused), 1:z_tensor, 2:w_u, 3:b_u, 4:w_l, 5:b_l, 6:y_tensor
  const float* z  = (const float*)d_in[1];
  const float* wu = (const float*)d_in[2];
  const float* bu = (const float*)d_in[3];
  const float* wl = (const float*)d_in[4];
  const float* bl = (const float*)d_in[5];
  const float* y  = (const float*)d_in[6];
  float* ws = (float*)d_ws;

  dim3 grid(NJT, BATCH);
  adv_main<<<grid, NTHREADS, 0, stream>>>(z, wu, bu, wl, bl, y, ws);
  adv_reduce<<<1, 64, 0, stream>>>(ws, (float*)d_out);
}

// Round 2
// 30.018 us; speedup vs baseline: 1.5307x; 1.5307x over previous
//
#include <hip/hip_runtime.h>
#include <math.h>

#define BATCH 32
#define ND 512
#define NC 100
#define JB 4
#define NJT 25          // NC / JB
#define NG 4            // n-groups per block (128 lanes each)
#define NT 512
#define NWAVE (NT/64)
#define BIGNEG 1000000.0f

__global__ __launch_bounds__(NT, 6) void adv_main(
    const float* __restrict__ z, const float* __restrict__ wu,
    const float* __restrict__ bu, const float* __restrict__ wl,
    const float* __restrict__ bl, const float* __restrict__ y,
    float* __restrict__ ws)
{
  // flat block id + XCD-chunked swizzle (800 % 8 == 0 -> bijective)
  int id = blockIdx.x + NJT * blockIdx.y;
  id = (id & 7) * (NJT * BATCH / 8) + (id >> 3);
  const int jt = id % NJT;
  const int b  = id / NJT;

  const int tid  = threadIdx.x;
  const int g    = tid >> 7;      // n-group 0..3
  const int lane = tid & 127;     // i index (active if < NC)

  __shared__ __align__(16) float s_cr[ND][2];   // center/radius interleaved
  __shared__ __align__(16) float s_wl[ND][JB];  // JB j-columns, 16B rows
  __shared__ float s_red[NG-1][128][5];         // acc[4]+accc partials, stride-5 (conflict-free)
  __shared__ float s_lin[NWAVE][JB];            // per-wave lin_l partials
  __shared__ float s_max[NWAVE];

  // stage center/radius: NT == ND, one row per thread
  const float* zb = z + b * (2 * ND);
  float lo = zb[tid], hi = zb[ND + tid];
  float cme = 0.5f * (lo + hi);
  float rad = 0.5f * (hi - lo);
  s_cr[tid][0] = cme;
  s_cr[tid][1] = rad;

  // stage w_l columns jt*JB..+3: one float4 row per thread (16B-aligned)
  const float* wlb = wl + (size_t)b * ND * NC + jt * JB;
  float4 wv = *(const float4*)(wlb + tid * NC);
  *(float4*)&s_wl[tid][0] = wv;

  // lin_l[jj] = sum_n c[n]*wl[n][jj] — own-register partials, wave shuffle-reduce
  float p0 = cme * wv.x, p1 = cme * wv.y, p2 = cme * wv.z, p3 = cme * wv.w;
#pragma unroll
  for (int off = 32; off; off >>= 1) {
    p0 += __shfl_down(p0, off, 64);
    p1 += __shfl_down(p1, off, 64);
    p2 += __shfl_down(p2, off, 64);
    p3 += __shfl_down(p3, off, 64);
  }
  if ((tid & 63) == 0) {
    s_lin[tid >> 6][0] = p0; s_lin[tid >> 6][1] = p1;
    s_lin[tid >> 6][2] = p2; s_lin[tid >> 6][3] = p3;
  }
  __syncthreads();

  float acc0 = 0.f, acc1 = 0.f, acc2 = 0.f, acc3 = 0.f, accc = 0.f;
  const int i = lane;
  const bool act = (i < NC);
  if (act) {
    const float* wub = wu + (size_t)b * ND * NC + (size_t)(g * (ND / NG)) * NC + i;
    const int n0 = g * (ND / NG), n1 = n0 + ND / NG;
#pragma unroll 4
    for (int n = n0; n < n1; ++n) {
      float w = *wub; wub += NC;                  // coalesced, L2-resident
      float c = s_cr[n][0], r = s_cr[n][1];       // broadcast ds_read
      float4 lv = *(const float4*)&s_wl[n][0];    // broadcast ds_read_b128
      accc = fmaf(c, w, accc);
      float d0 = w - lv.x; acc0 = fmaf(r, fabsf(d0), acc0);
      float d1 = w - lv.y; acc1 = fmaf(r, fabsf(d1), acc1);
      float d2 = w - lv.z; acc2 = fmaf(r, fabsf(d2), acc2);
      float d3 = w - lv.w; acc3 = fmaf(r, fabsf(d3), acc3);
    }
  }

  // cross-n-group reduction: groups 1..3 dump, group 0 combines
  if (g > 0) {
    float* pr = &s_red[g - 1][lane][0];
    pr[0] = acc0; pr[1] = acc1; pr[2] = acc2; pr[3] = acc3; pr[4] = accc;
  }
  __syncthreads();

  float m = -INFINITY;
  if (g == 0 && act) {
    float L0 = 0.f, L1 = 0.f, L2 = 0.f, L3 = 0.f;
#pragma unroll
    for (int w = 0; w < NWAVE; ++w) {
      L0 += s_lin[w][0]; L1 += s_lin[w][1]; L2 += s_lin[w][2]; L3 += s_lin[w][3];
    }
    float a0 = acc0, a1 = acc1, a2 = acc2, a3 = acc3, aT = accc;
#pragma unroll
    for (int gg = 0; gg < NG - 1; ++gg) {
      const float* pr = &s_red[gg][lane][0];
      a0 += pr[0]; a1 += pr[1]; a2 += pr[2]; a3 += pr[3]; aT += pr[4];
    }
    const float* bub = bu + b * NC;
    const float* blb = bl + b * NC;
    const float* yb  = y  + b * NC;
    const int j0 = jt * JB;
    float base_i = bub[i] - BIGNEG * yb[i] + aT;
    float v0 = a0 + base_i - blb[j0 + 0] - BIGNEG * (1.0f - yb[j0 + 0]) - L0;
    float v1 = a1 + base_i - blb[j0 + 1] - BIGNEG * (1.0f - yb[j0 + 1]) - L1;
    float v2 = a2 + base_i - blb[j0 + 2] - BIGNEG * (1.0f - yb[j0 + 2]) - L2;
    float v3 = a3 + base_i - blb[j0 + 3] - BIGNEG * (1.0f - yb[j0 + 3]) - L3;
    m = fmaxf(fmaxf(v0, v1), fmaxf(v2, v3));
  }

  // block max-reduce (inactive threads carry -inf)
#pragma unroll
  for (int off = 32; off; off >>= 1) m = fmaxf(m, __shfl_down(m, off, 64));
  if ((tid & 63) == 0) s_max[tid >> 6] = m;
  __syncthreads();
  if (tid == 0) {
    float r = s_max[0];
#pragma unroll
    for (int wv2 = 1; wv2 < NWAVE; ++wv2) r = fmaxf(r, s_max[wv2]);
    ws[b * NJT + jt] = r;
  }
}

__global__ void adv_reduce(const float* __restrict__ ws, float* __restrict__ out) {
  int b = threadIdx.x;
  if (b < BATCH) {
    float m = -INFINITY;
#pragma unroll
    for (int jt = 0; jt < NJT; ++jt) m = fmaxf(m, ws[b * NJT + jt]);
    out[b] = m;
  }
}

extern "C" void kernel_launch(void* const* d_in, const int* in_sizes, int n_in,
                              void* d_out, int out_size, void* d_ws, size_t ws_size,
                              hipStream_t stream) {
  // inputs: 0:x (unused), 1:z_tensor, 2:w_u, 3:b_u, 4:w_l, 5:b_l, 6:y_tensor
  const float* z  = (const float*)d_in[1];
  const float* wu = (const float*)d_in[2];
  const float* bu = (const float*)d_in[3];
  const float* wl = (const float*)d_in[4];
  const float* bl = (const float*)d_in[5];
  const float* y  = (const float*)d_in[6];
  float* ws = (float*)d_ws;

  dim3 grid(NJT, BATCH);
  adv_main<<<grid, NT, 0, stream>>>(z, wu, bu, wl, bl, y, ws);
  adv_reduce<<<1, 64, 0, stream>>>(ws, (float*)d_out);
}

// Round 4
// 28.447 us; speedup vs baseline: 1.6152x; 1.0552x over previous
//
#include <hip/hip_runtime.h>
#include <math.h>
#include <stdint.h>

#define BATCH 32
#define ND 512
#define NC 100
#define JB 8
#define NJT 13          // tiles at j0 = 0,8,...,88, and last tile j0=92 (overlap, max-idempotent)
#define NG 4            // n-groups of 128
#define NT 512
#define NWAVE 8
#define BIGNEG 1000000.0f

typedef float f32x8 __attribute__((ext_vector_type(8)));

__global__ __launch_bounds__(NT, 4) void adv_main(
    const float* __restrict__ z, const float* __restrict__ wu,
    const float* __restrict__ bu, const float* __restrict__ wl,
    const float* __restrict__ bl, const float* __restrict__ y,
    float* __restrict__ ws)
{
  // XCD-chunk swizzle: 416 = 8*52, bijective
  int id = (blockIdx.x & 7) * (NJT * BATCH / 8) + (blockIdx.x >> 3);
  const int b  = id / NJT;
  const int jt = id - b * NJT;
  const int j0 = (jt < NJT - 1) ? jt * JB : (NC - JB);   // 92 for last tile

  const int tid  = threadIdx.x;
  const int g    = tid >> 7;        // n-group (wave-uniform: 2 waves per g)
  const int lane = tid & 127;       // i index
  const int iL   = (lane < NC) ? lane : NC - 1;   // clamp dead lanes

  __shared__ __align__(16) float s_cr[ND][2];
  __shared__ float s_red[NG - 1][128][9];   // 8 acc + accc, stride 9
  __shared__ float s_lin[NWAVE][JB];
  __shared__ float s_max[NWAVE];

  // ---- staging: thread tid <-> n=tid (NT == ND) ----
  const float* zb = z + b * (2 * ND);
  float lo = zb[tid], hi = zb[ND + tid];
  float cme = 0.5f * (lo + hi);
  float rad = 0.5f * (hi - lo);
  s_cr[tid][0] = cme;
  s_cr[tid][1] = rad;

  // lin_l partials: p[jj] = cme * wl[b][tid][j0+jj]  (row base + j0 is 16B-aligned)
  const float* wlr = wl + (size_t)b * ND * NC + (size_t)tid * NC + j0;
  float4 wa = *(const float4*)wlr;
  float4 wb = *(const float4*)(wlr + 4);
  float p[JB] = {cme * wa.x, cme * wa.y, cme * wa.z, cme * wa.w,
                 cme * wb.x, cme * wb.y, cme * wb.z, cme * wb.w};
#pragma unroll
  for (int off = 32; off; off >>= 1) {
#pragma unroll
    for (int jj = 0; jj < JB; ++jj) p[jj] += __shfl_down(p[jj], off, 64);
  }
  if ((tid & 63) == 0) {
#pragma unroll
    for (int jj = 0; jj < JB; ++jj) s_lin[tid >> 6][jj] = p[jj];
  }
  __syncthreads();

  // ---- main loop: 32 chunks x 4 n ----
  float acc[JB] = {0, 0, 0, 0, 0, 0, 0, 0};
  float accc = 0.f;
  const float* wup = wu + (size_t)b * ND * NC + (size_t)(g * 128) * NC + iL;
  const float* crp = &s_cr[g * 128][0];

  // wl stream base: wave-uniform -> force into SGPRs via readfirstlane halves
  uint64_t va = (uint64_t)(wl + (size_t)b * ND * NC + (size_t)(g * 128) * NC + j0);
  uint32_t lo32 = __builtin_amdgcn_readfirstlane((uint32_t)(va & 0xffffffffu));
  uint32_t hi32 = __builtin_amdgcn_readfirstlane((uint32_t)(va >> 32));
  uint64_t sa = ((uint64_t)hi32 << 32) | (uint64_t)lo32;

  for (int ch = 0; ch < 32; ++ch) {
    float w0 = wup[0], w1 = wup[NC], w2 = wup[2 * NC], w3 = wup[3 * NC];
    f32x8 q0, q1, q2, q3;
    asm volatile(
        "s_load_dwordx8 %0, %4, 0x0\n\t"
        "s_load_dwordx8 %1, %4, 0x190\n\t"
        "s_load_dwordx8 %2, %4, 0x320\n\t"
        "s_load_dwordx8 %3, %4, 0x4b0\n\t"
        "s_waitcnt lgkmcnt(0)"
        : "=&s"(q0), "=&s"(q1), "=&s"(q2), "=&s"(q3)
        : "s"(sa));
    float c0 = crp[0], r0 = crp[1];
    accc = fmaf(c0, w0, accc);
#pragma unroll
    for (int jj = 0; jj < JB; ++jj) acc[jj] = fmaf(r0, fabsf(q0[jj] - w0), acc[jj]);
    float c1 = crp[2], r1 = crp[3];
    accc = fmaf(c1, w1, accc);
#pragma unroll
    for (int jj = 0; jj < JB; ++jj) acc[jj] = fmaf(r1, fabsf(q1[jj] - w1), acc[jj]);
    float c2 = crp[4], r2 = crp[5];
    accc = fmaf(c2, w2, accc);
#pragma unroll
    for (int jj = 0; jj < JB; ++jj) acc[jj] = fmaf(r2, fabsf(q2[jj] - w2), acc[jj]);
    float c3 = crp[6], r3 = crp[7];
    accc = fmaf(c3, w3, accc);
#pragma unroll
    for (int jj = 0; jj < JB; ++jj) acc[jj] = fmaf(r3, fabsf(q3[jj] - w3), acc[jj]);
    wup += 4 * NC; crp += 8;
    sa  += 4 * NC * sizeof(float);   // scalar add (uniform)
  }

  // ---- cross-group reduction ----
  if (g > 0) {
    float* pr = &s_red[g - 1][lane][0];
#pragma unroll
    for (int jj = 0; jj < JB; ++jj) pr[jj] = acc[jj];
    pr[JB] = accc;
  }
  __syncthreads();

  float m = -INFINITY;
  if (g == 0 && lane < NC) {
    float L[JB];
#pragma unroll
    for (int jj = 0; jj < JB; ++jj) L[jj] = s_lin[0][jj];
#pragma unroll
    for (int w = 1; w < NWAVE; ++w)
#pragma unroll
      for (int jj = 0; jj < JB; ++jj) L[jj] += s_lin[w][jj];

    float a[JB], aT = accc;
#pragma unroll
    for (int jj = 0; jj < JB; ++jj) a[jj] = acc[jj];
#pragma unroll
    for (int gg = 0; gg < NG - 1; ++gg) {
      const float* pr = &s_red[gg][lane][0];
#pragma unroll
      for (int jj = 0; jj < JB; ++jj) a[jj] += pr[jj];
      aT += pr[JB];
    }
    const float* bub = bu + b * NC;
    const float* blb = bl + b * NC;
    const float* yb  = y  + b * NC;
    float base_i = bub[lane] - BIGNEG * yb[lane] + aT;
#pragma unroll
    for (int jj = 0; jj < JB; ++jj) {
      int j = j0 + jj;
      float v = a[jj] + base_i - blb[j] - BIGNEG * (1.0f - yb[j]) - L[jj];
      m = fmaxf(m, v);
    }
  }

#pragma unroll
  for (int off = 32; off; off >>= 1) m = fmaxf(m, __shfl_down(m, off, 64));
  if ((tid & 63) == 0) s_max[tid >> 6] = m;
  __syncthreads();
  if (tid == 0) {
    float r = s_max[0];
#pragma unroll
    for (int wv = 1; wv < NWAVE; ++wv) r = fmaxf(r, s_max[wv]);
    ws[b * NJT + jt] = r;
  }
}

__global__ void adv_reduce(const float* __restrict__ ws, float* __restrict__ out) {
  int b = threadIdx.x;
  if (b < BATCH) {
    float m = -INFINITY;
#pragma unroll
    for (int jt = 0; jt < NJT; ++jt) m = fmaxf(m, ws[b * NJT + jt]);
    out[b] = m;
  }
}

extern "C" void kernel_launch(void* const* d_in, const int* in_sizes, int n_in,
                              void* d_out, int out_size, void* d_ws, size_t ws_size,
                              hipStream_t stream) {
  // inputs: 0:x (unused), 1:z_tensor, 2:w_u, 3:b_u, 4:w_l, 5:b_l, 6:y_tensor
  const float* z  = (const float*)d_in[1];
  const float* wu = (const float*)d_in[2];
  const float* bu = (const float*)d_in[3];
  const float* wl = (const float*)d_in[4];
  const float* bl = (const float*)d_in[5];
  const float* y  = (const float*)d_in[6];
  float* ws = (float*)d_ws;

  adv_main<<<NJT * BATCH, NT, 0, stream>>>(z, wu, bu, wl, bl, y, ws);
  adv_reduce<<<1, 64, 0, stream>>>(ws, (float*)d_out);
}